// Round 9
// baseline (120.711 us; speedup 1.0000x reference)
//
#include <hip/hip_runtime.h>
#include <hip/hip_bf16.h>
#include <cstdint>

typedef _Float16 f16;
typedef _Float16 f16x8 __attribute__((ext_vector_type(8)));
typedef _Float16 f16x4 __attribute__((ext_vector_type(4)));
typedef float    f32x4 __attribute__((ext_vector_type(4)));

#define DH 128

// Packed f16 weight layout (fragments for v_mfma_f32_16x16x32_f16):
//   packed[((ct*NKS + ks)*64 + lane)*8 + i] = W[rb + ks*32 + (lane>>4)*8 + i][ct*16 + (lane&15)]
#define PK_W0   0
#define PK_W1   16384
#define PK_W2   32768
#define PK_WG   49152
#define PK_R0A  65536
#define PK_R0B  81920
#define PK_R1   98304
#define PK_TOTAL 106496

__global__ void pack_weights_kernel(const float* __restrict__ W0, const float* __restrict__ W1,
                                    const float* __restrict__ W2, const float* __restrict__ Wg,
                                    const float* __restrict__ R0, const float* __restrict__ R1,
                                    f16* __restrict__ pk)
{
    int t = blockIdx.x * 256 + threadIdx.x;
    const float* W; int K, NC, local, rb = 0; f16* dst;
    if      (t < 2048)  { W = W0; K = 128; NC = 128; local = t;          dst = pk + PK_W0;  }
    else if (t < 4096)  { W = W1; K = 128; NC = 128; local = t - 2048;   dst = pk + PK_W1;  }
    else if (t < 6144)  { W = W2; K = 128; NC = 128; local = t - 4096;   dst = pk + PK_W2;  }
    else if (t < 8192)  { W = Wg; K = 128; NC = 128; local = t - 6144;   dst = pk + PK_WG;  }
    else if (t < 10240) { W = R0; K = 128; NC = 128; local = t - 8192;   dst = pk + PK_R0A; }
    else if (t < 12288) { W = R0; K = 128; NC = 128; local = t - 10240;  dst = pk + PK_R0B; rb = 128; }
    else if (t < 13312) { W = R1; K = 128; NC = 64;  local = t - 12288;  dst = pk + PK_R1;  }
    else return;
    int lane = local & 63;
    int frag = local >> 6;
    int nks  = K >> 5;
    int ks   = frag % nks;
    int ct   = frag / nks;
    int row0 = rb + ks * 32 + ((lane >> 4) << 3);
    int col  = ct * 16 + (lane & 15);
    f16x8 v;
    #pragma unroll
    for (int i = 0; i < 8; ++i) v[i] = (f16)W[(size_t)(row0 + i) * NC + col];
    *(f16x8*)(dst + (size_t)local * 8) = v;
}

// ---------------- Node phase: x = sigmoid(z@Wg+bg)*z; u = x@R0a + r0; v = x@R0b
// 128 nodes/block, 4 waves; wave w owns rows [32w,32w+32) as two 16-row tiles
// sharing every B-fragment load. SINGLE LDS buffer used in place (rows are
// wave-private; A-frags fully in registers before any overwrite). u/v are
// staged back into the LDS buffer and written with coalesced uint4 copy_out
// (round-7 lesson: direct per-f16 global stores cost ~22 us in write amp).
__global__ __launch_bounds__(256, 2)
void node_mlp_mfma(const float* __restrict__ h, const f16* __restrict__ pk,
                   const float* __restrict__ b0, const float* __restrict__ b1,
                   const float* __restrict__ b2, const float* __restrict__ bg,
                   const float* __restrict__ r0,
                   f16* __restrict__ ug, f16* __restrict__ vg, int N)
{
    __shared__ f16 zA[128 * 136];          // 34.8 KB -> up to 4 blocks/CU
    const int t = threadIdx.x;
    const int lane = t & 63;
    const int w = t >> 6;
    const int n0 = blockIdx.x * 128;

    // stage h -> zA as f16 (coalesced float4 loads)
    {
        int c4 = t & 31, rr = t >> 5;
        #pragma unroll
        for (int i = 0; i < 16; ++i) {
            int r = rr + 8 * i;
            int node = n0 + r; if (node >= N) node = N - 1;
            float4 v = *(const float4*)(h + (size_t)node * DH + c4 * 4);
            f16x4 o; o[0] = (f16)v.x; o[1] = (f16)v.y; o[2] = (f16)v.z; o[3] = (f16)v.w;
            *(f16x4*)(&zA[r * 136 + c4 * 4]) = o;
        }
    }
    __syncthreads();

    const int lr = lane & 15;
    const int lg = lane >> 4;
    const int rowA = w * 32 + lr;

    // in-place layer; mode: 0=relu, 1=gate (sigmoid(acc+b)*z)
    auto layer_ip = [&](const f16* pw, const float* bias, int mode) {
        f16x8 A0[4], A1[4];
        #pragma unroll
        for (int ks = 0; ks < 4; ++ks) {
            A0[ks] = *(const f16x8*)(&zA[rowA * 136 + ks * 32 + lg * 8]);
            A1[ks] = *(const f16x8*)(&zA[(rowA + 16) * 136 + ks * 32 + lg * 8]);
        }
        #pragma unroll
        for (int ct = 0; ct < 8; ++ct) {
            f32x4 acc0 = {0.f, 0.f, 0.f, 0.f};
            f32x4 acc1 = {0.f, 0.f, 0.f, 0.f};
            #pragma unroll
            for (int ks = 0; ks < 4; ++ks) {
                f16x8 B = *(const f16x8*)(pw + ((ct * 4 + ks) * 64 + lane) * 8);
                acc0 = __builtin_amdgcn_mfma_f32_16x16x32_f16(A0[ks], B, acc0, 0, 0, 0);
                acc1 = __builtin_amdgcn_mfma_f32_16x16x32_f16(A1[ks], B, acc1, 0, 0, 0);
            }
            float bj = bias[ct * 16 + lr];
            #pragma unroll
            for (int r = 0; r < 4; ++r) {
                int c = ct * 16 + lr;
                int row0 = w * 32 + lg * 4 + r;
                int row1 = row0 + 16;
                float v0 = acc0[r] + bj;
                float v1 = acc1[r] + bj;
                if (mode == 0) {
                    v0 = fmaxf(v0, 0.f); v1 = fmaxf(v1, 0.f);
                } else {
                    float g0 = 1.f / (1.f + __expf(-v0));
                    float g1 = 1.f / (1.f + __expf(-v1));
                    v0 = g0 * (float)zA[row0 * 136 + c];
                    v1 = g1 * (float)zA[row1 * 136 + c];
                }
                zA[row0 * 136 + c] = (f16)v0;
                zA[row1 * 136 + c] = (f16)v1;
            }
        }
    };

    auto copy_out = [&](f16* gdst) {
        int c8 = t & 15, rr = t >> 4;
        #pragma unroll
        for (int i = 0; i < 8; ++i) {
            int r = rr + 16 * i;
            int node = n0 + r;
            if (node < N) {
                uint4 vv = *(const uint4*)(&zA[r * 136 + c8 * 8]);
                *(uint4*)(gdst + (size_t)node * DH + c8 * 8) = vv;
            }
        }
    };

    layer_ip(pk + PK_W0, b0, 0);
    layer_ip(pk + PK_W1, b1, 0);
    layer_ip(pk + PK_W2, b2, 0);
    layer_ip(pk + PK_WG, bg, 1);

    // A-frags of x held in registers across both output GEMMs (x is then dead
    // in LDS, so u/v can overwrite zA in place for the coalesced copy_out).
    f16x8 A0[4], A1[4];
    #pragma unroll
    for (int ks = 0; ks < 4; ++ks) {
        A0[ks] = *(const f16x8*)(&zA[rowA * 136 + ks * 32 + lg * 8]);
        A1[ks] = *(const f16x8*)(&zA[(rowA + 16) * 136 + ks * 32 + lg * 8]);
    }

    // u = x @ R0a + r0 -> zA -> ug
    #pragma unroll
    for (int ct = 0; ct < 8; ++ct) {
        f32x4 acc0 = {0.f,0.f,0.f,0.f}, acc1 = {0.f,0.f,0.f,0.f};
        #pragma unroll
        for (int ks = 0; ks < 4; ++ks) {
            f16x8 B = *(const f16x8*)(pk + PK_R0A + ((ct * 4 + ks) * 64 + lane) * 8);
            acc0 = __builtin_amdgcn_mfma_f32_16x16x32_f16(A0[ks], B, acc0, 0, 0, 0);
            acc1 = __builtin_amdgcn_mfma_f32_16x16x32_f16(A1[ks], B, acc1, 0, 0, 0);
        }
        float bj = r0[ct * 16 + lr];
        #pragma unroll
        for (int r = 0; r < 4; ++r) {
            int c = ct * 16 + lr;
            int row0 = w * 32 + lg * 4 + r;
            zA[row0 * 136 + c] = (f16)(acc0[r] + bj);
            zA[(row0 + 16) * 136 + c] = (f16)(acc1[r] + bj);
        }
    }
    __syncthreads();
    copy_out(ug);
    __syncthreads();   // all copy_out reads done before v overwrites

    // v = x @ R0b -> zA -> vg
    #pragma unroll
    for (int ct = 0; ct < 8; ++ct) {
        f32x4 acc0 = {0.f,0.f,0.f,0.f}, acc1 = {0.f,0.f,0.f,0.f};
        #pragma unroll
        for (int ks = 0; ks < 4; ++ks) {
            f16x8 B = *(const f16x8*)(pk + PK_R0B + ((ct * 4 + ks) * 64 + lane) * 8);
            acc0 = __builtin_amdgcn_mfma_f32_16x16x32_f16(A0[ks], B, acc0, 0, 0, 0);
            acc1 = __builtin_amdgcn_mfma_f32_16x16x32_f16(A1[ks], B, acc1, 0, 0, 0);
        }
        #pragma unroll
        for (int r = 0; r < 4; ++r) {
            int c = ct * 16 + lr;
            int row0 = w * 32 + lg * 4 + r;
            zA[row0 * 136 + c] = (f16)acc0[r];
            zA[(row0 + 16) * 136 + c] = (f16)acc1[r];
        }
    }
    __syncthreads();
    copy_out(vg);
}

// ---------------- Edge phase: out = (relu(relu(u[src]+v[dst]) @ R1 + r1)) @ R2 + r2
// Zero LDS. Wave-independent: 16 edges per wave-iteration, grid-stride.
// R1 fragments persist in VGPRs; gather lands directly in MFMA fragment regs.
// Measured wall (r4/5/7/8): ~11.8 cyc per gathered 128B line per CU — an
// outstanding-miss throughput cap. 4 lines/edge is structural (u,v rows fully
// consumed); src-bucketing cut HBM fetch 35% with zero time change (r8), so
// locality levers are exhausted. Keep exactly the verified 66 us config.
// NOTE: launch_bounds must stay (256,2) — (256,5) spills Bw[16] (round 6).
__global__ __launch_bounds__(256, 2)
void edge_mlp_v3(const f16* __restrict__ u, const f16* __restrict__ v,
                 const int* __restrict__ src, const int* __restrict__ dst,
                 const f16* __restrict__ pk,
                 const float* __restrict__ r1, const float* __restrict__ R2,
                 const float* __restrict__ r2,
                 float* __restrict__ out, int E, int ngroups, int nwaves)
{
    const int t = threadIdx.x;
    const int lane = t & 63;
    const int lr = lane & 15, lg = lane >> 4;
    const int wid = (int)((blockIdx.x * blockDim.x + t) >> 6);

    f16x8 Bw[16];
    #pragma unroll
    for (int f = 0; f < 16; ++f)
        Bw[f] = *(const f16x8*)(pk + PK_R1 + ((size_t)(f * 64 + lane)) * 8);

    f32x4 r1f[4];
    #pragma unroll
    for (int ct = 0; ct < 4; ++ct)
        r1f[ct] = *(const f32x4*)(r1 + ct * 16 + lg * 4);

    float R2f0[16], R2f1[16];
    #pragma unroll
    for (int ct = 0; ct < 4; ++ct)
        #pragma unroll
        for (int r = 0; r < 4; ++r) {
            int k = ct * 16 + lg * 4 + r;
            R2f0[ct * 4 + r] = R2[k * 2 + 0];
            R2f1[ct * 4 + r] = R2[k * 2 + 1];
        }
    const float ob0 = r2[0], ob1 = r2[1];

    int g = wid;
    if (g >= ngroups) return;

    int e0 = g * 16 + lr; if (e0 >= E) e0 = E - 1;
    int sc = src[e0], dc = dst[e0];
    f16x8 Uc[4], Vc[4];
    {
        const f16* ur = u + (size_t)sc * DH + lg * 8;
        const f16* vr = v + (size_t)dc * DH + lg * 8;
        #pragma unroll
        for (int ks = 0; ks < 4; ++ks) {
            Uc[ks] = *(const f16x8*)(ur + ks * 32);
            Vc[ks] = *(const f16x8*)(vr + ks * 32);
        }
    }
    int sn = 0, dn = 0;
    if (g + nwaves < ngroups) {
        int en = (g + nwaves) * 16 + lr; if (en >= E) en = E - 1;
        sn = src[en]; dn = dst[en];
    }

    while (g < ngroups) {
        const int gnext = g + nwaves;
        f16x8 Un[4], Vn[4];
        if (gnext < ngroups) {
            const f16* ur = u + (size_t)sn * DH + lg * 8;
            const f16* vr = v + (size_t)dn * DH + lg * 8;
            #pragma unroll
            for (int ks = 0; ks < 4; ++ks) {
                Un[ks] = *(const f16x8*)(ur + ks * 32);
                Vn[ks] = *(const f16x8*)(vr + ks * 32);
            }
        }
        int g2 = g + 2 * nwaves;
        int s2 = 0, d2 = 0;
        if (g2 < ngroups) {
            int e2 = g2 * 16 + lr; if (e2 >= E) e2 = E - 1;
            s2 = src[e2]; d2 = dst[e2];
        }

        // y1 fragments: relu(u + v)  (r0 folded into u)
        f16x8 A[4];
        #pragma unroll
        for (int ks = 0; ks < 4; ++ks) {
            f16x8 s = Uc[ks] + Vc[ks];
            #pragma unroll
            for (int i = 0; i < 8; ++i) s[i] = s[i] > (f16)0 ? s[i] : (f16)0;
            A[ks] = s;
        }

        // L2 GEMM (swapped): D[outcol][edge], lane holds edge (lane&15)
        f32x4 a0 = {0.f,0.f,0.f,0.f}, a1 = {0.f,0.f,0.f,0.f};
        f32x4 a2 = {0.f,0.f,0.f,0.f}, a3 = {0.f,0.f,0.f,0.f};
        #pragma unroll
        for (int ks = 0; ks < 4; ++ks) {
            a0 = __builtin_amdgcn_mfma_f32_16x16x32_f16(Bw[0*4+ks], A[ks], a0, 0, 0, 0);
            a1 = __builtin_amdgcn_mfma_f32_16x16x32_f16(Bw[1*4+ks], A[ks], a1, 0, 0, 0);
            a2 = __builtin_amdgcn_mfma_f32_16x16x32_f16(Bw[2*4+ks], A[ks], a2, 0, 0, 0);
            a3 = __builtin_amdgcn_mfma_f32_16x16x32_f16(Bw[3*4+ks], A[ks], a3, 0, 0, 0);
        }

        // bias + relu + L3 partial dot; r2 bias added once by writing lane
        float p0 = 0.f, p1 = 0.f;
        #pragma unroll
        for (int r = 0; r < 4; ++r) {
            float y;
            y = fmaxf(a0[r] + r1f[0][r], 0.f); p0 = fmaf(y, R2f0[0*4+r], p0); p1 = fmaf(y, R2f1[0*4+r], p1);
            y = fmaxf(a1[r] + r1f[1][r], 0.f); p0 = fmaf(y, R2f0[1*4+r], p0); p1 = fmaf(y, R2f1[1*4+r], p1);
            y = fmaxf(a2[r] + r1f[2][r], 0.f); p0 = fmaf(y, R2f0[2*4+r], p0); p1 = fmaf(y, R2f1[2*4+r], p1);
            y = fmaxf(a3[r] + r1f[3][r], 0.f); p0 = fmaf(y, R2f0[3*4+r], p0); p1 = fmaf(y, R2f1[3*4+r], p1);
        }
        float q;
        q = __shfl_xor(p0, 16); p0 += q;
        q = __shfl_xor(p0, 32); p0 += q;
        q = __shfl_xor(p1, 16); p1 += q;
        q = __shfl_xor(p1, 32); p1 += q;
        int eo = g * 16 + lr;
        if (lg == 0 && eo < E)
            *(float2*)(out + (size_t)eo * 2) = make_float2(p0 + ob0, p1 + ob1);

        #pragma unroll
        for (int ks = 0; ks < 4; ++ks) { Uc[ks] = Un[ks]; Vc[ks] = Vn[ks]; }
        sc = sn; dc = dn; sn = s2; dn = d2;
        g = gnext;
    }
}

extern "C" void kernel_launch(void* const* d_in, const int* in_sizes, int n_in,
                              void* d_out, int out_size, void* d_ws, size_t ws_size,
                              hipStream_t stream)
{
    const float* h   = (const float*)d_in[0];
    const int*   src = (const int*)d_in[1];
    const int*   dst = (const int*)d_in[2];
    const float* W0  = (const float*)d_in[3];
    const float* b0  = (const float*)d_in[4];
    const float* W1  = (const float*)d_in[5];
    const float* b1  = (const float*)d_in[6];
    const float* W2  = (const float*)d_in[7];
    const float* b2  = (const float*)d_in[8];
    const float* Wg  = (const float*)d_in[9];
    const float* bg  = (const float*)d_in[10];
    const float* R0  = (const float*)d_in[11];
    const float* r0  = (const float*)d_in[12];
    const float* R1  = (const float*)d_in[13];
    const float* r1  = (const float*)d_in[14];
    const float* R2  = (const float*)d_in[15];
    const float* r2  = (const float*)d_in[16];

    const int N = in_sizes[0] / DH;
    const int E = in_sizes[1];

    f16* pk = (f16*)d_ws;                        // 208 KB packed weights
    f16* ug = pk + PK_TOTAL;                     // N*128 f16
    f16* vg = ug + (size_t)N * DH;               // N*128 f16

    pack_weights_kernel<<<dim3(52), dim3(256), 0, stream>>>(W0, W1, W2, Wg, R0, R1, pk);
    node_mlp_mfma<<<dim3((N + 127) / 128), dim3(256), 0, stream>>>(
        h, pk, b0, b1, b2, bg, r0, ug, vg, N);

    const int ngroups = (E + 15) / 16;
    const int nblocks = 1024;
    const int nwaves  = nblocks * 4;
    edge_mlp_v3<<<dim3(nblocks), dim3(256), 0, stream>>>(
        ug, vg, src, dst, pk, r1, R2, r2, (float*)d_out, E, ngroups, nwaves);
}